// Round 9
// baseline (447.919 us; speedup 1.0000x reference)
//
#include <hip/hip_runtime.h>

// ---------- bf16 helpers (raw ushort bit ops, RNE store) ----------
__device__ __forceinline__ float bf2f(unsigned short u) {
  union { unsigned int i; float f; } c; c.i = ((unsigned int)u) << 16; return c.f;
}
__device__ __forceinline__ unsigned short f2bf(float f) {
  union { float f; unsigned int i; } c; c.f = f;
  unsigned int x = c.i;
  return (unsigned short)((x + 0x7fffu + ((x >> 16) & 1u)) >> 16);
}
__device__ __forceinline__ float lo16(unsigned int w) { return bf2f((unsigned short)(w & 0xffffu)); }
__device__ __forceinline__ float hi16(unsigned int w) { return bf2f((unsigned short)(w >> 16)); }

#define DD 128
#define HH 64
#define CC 40
#define NBUCK 64
#define SLOTS 28          // LDS staging slots per bucket in bucketA
#define MAXNPB 2048       // max nodes per bucket supported (N <= 131072)

// ---------- dtype detect ----------
__global__ void detect(const unsigned int* e32, const unsigned int* x32, int* flags) {
  __shared__ unsigned int redOr[256];
  __shared__ int redCnt[256];
  int tid = threadIdx.x;
  unsigned int v = 0;
  for (int i = tid; i < 4096; i += 256) v |= e32[2 * i + 1];
  int cnt = 0;
  for (int i = tid; i < 4096; i += 256) {
    unsigned int w = x32[i];
    unsigned int expo = (w >> 7) & 0xffu;
    unsigned short lo = (unsigned short)(w & 0xffffu);
    if (lo == 0 || (expo >= 100u && expo <= 133u)) cnt++;
  }
  redOr[tid] = v; redCnt[tid] = cnt; __syncthreads();
  for (int s = 128; s > 0; s >>= 1) {
    if (tid < s) { redOr[tid] |= redOr[tid + s]; redCnt[tid] += redCnt[tid + s]; }
    __syncthreads();
  }
  if (tid == 0) {
    flags[0] = (redOr[0] == 0u) ? 1 : 0;
    flags[1] = (redCnt[0] < 2048) ? 1 : 0;
  }
}

// ---------- bucketA: LDS-staged scatter of (src,dst) into per-bucket segments ----------
// Each block owns a contiguous edge chunk; flushes >=16 entries (>=128B contiguous).
__global__ __launch_bounds__(256) void bucketA(const int* e32, int E, int N,
                                               const int* flags, int nodesPerB, int cap,
                                               uint2* ebuf, int* gcur) {
  __shared__ uint2 buf[NBUCK][SLOTS];        // 14 KB
  __shared__ int cnt[NBUCK];
  int tid = threadIdx.x;
  if (tid < NBUCK) cnt[tid] = 0;
  __syncthreads();
  int isI64 = flags[0];
  int chunk = (E + gridDim.x - 1) / gridDim.x;
  int e0 = blockIdx.x * chunk;
  int e1 = min(e0 + chunk, E);
  if (e0 >= e1) return;
  for (int base = e0; base < e1; base += 256) {
    int i = base + tid;
    if (i < e1) {
      int s, d;
      if (isI64) { s = e32[2 * i]; d = e32[2 * (E + i)]; }
      else       { s = e32[i];     d = e32[E + i]; }
      s = min(max(s, 0), N - 1);
      d = min(max(d, 0), N - 1);
      int b = d / nodesPerB;
      int slot = atomicAdd(&cnt[b], 1);
      if (slot < SLOTS) buf[b][slot] = make_uint2((unsigned)s, (unsigned)d);
      else {                                   // rare overflow: direct scatter
        int p = atomicAdd(&gcur[b], 1);
        if (p < cap) ebuf[(size_t)b * cap + p] = make_uint2((unsigned)s, (unsigned)d);
      }
    }
    __syncthreads();
    bool last = (base + 256 >= e1);
    if (tid < NBUCK) {
      int c = min(cnt[tid], SLOTS);
      if (c > 0 && (c >= 16 || last)) {
        int p = atomicAdd(&gcur[tid], c);
        for (int k = 0; k < c; k++) {
          int pp = p + k;
          if (pp < cap) ebuf[(size_t)tid * cap + pp] = buf[tid][k];
        }
        cnt[tid] = 0;
      }
    }
    __syncthreads();
  }
}

// ---------- bscan (+ prep_w on block 1): exclusive scan of bucket totals ----------
// Wp1f[p*64+j] = {W1l[2p][j], W1l[2p+1][j], W1r[2p][j], W1r[2p+1][j]}  (p<64)
// Wc2f[p*64+j] = {Wcat[2p][j], Wcat[2p+1][j]} for j<40 else {0,0}      (p<64)
__global__ void bscan_prepw(const int* gcur, int nbuck, int cap, int* bbase,
                            int* row_ptr, int N,
                            const void* W1l, const void* W1r, const void* b1,
                            const void* W2l, const void* W2r, const void* b2,
                            const int* flags, float4* Wp1f, float2* Wc2f,
                            float* b1f, float* b2f) {
  int tid = threadIdx.x;
  if (blockIdx.x == 1) {                       // prep_w role
    int isf = flags[1];
    auto rd = [&](const void* p, int i) -> float {
      return isf ? ((const float*)p)[i] : bf2f(((const unsigned short*)p)[i]);
    };
    auto wcat = [&](int k, int j) -> float {
      return (k < HH) ? rd(W2l, k * CC + j) : rd(W2r, (k - HH) * CC + j);
    };
    for (int idx = tid; idx < 64 * 64; idx += 256) {
      int p = idx >> 6, j = idx & 63;
      Wp1f[idx] = make_float4(rd(W1l, (2 * p) * HH + j), rd(W1l, (2 * p + 1) * HH + j),
                              rd(W1r, (2 * p) * HH + j), rd(W1r, (2 * p + 1) * HH + j));
      Wc2f[idx] = (j < CC) ? make_float2(wcat(2 * p, j), wcat(2 * p + 1, j))
                           : make_float2(0.f, 0.f);
    }
    if (tid < HH) b1f[tid] = rd(b1, tid);
    if (tid < CC) b2f[tid] = rd(b2, tid);
    return;
  }
  __shared__ int tmp[NBUCK];
  int v = 0;
  if (tid < NBUCK) {
    v = (tid < nbuck) ? min(gcur[tid], cap) : 0;
    tmp[tid] = v;
  }
  __syncthreads();
  for (int st = 1; st < NBUCK; st <<= 1) {
    int t = (tid >= st && tid < NBUCK) ? tmp[tid - st] : 0;
    __syncthreads();
    if (tid < NBUCK) tmp[tid] += t;
    __syncthreads();
  }
  if (tid < NBUCK) bbase[tid] = tmp[tid] - v;  // exclusive
  if (tid == 0) row_ptr[N] = tmp[NBUCK - 1];
}

// ---------- hybrid: bucketB (CSR finalize, L2-local) ∥ transform1 (VALU-bound) ----------
__global__ __launch_bounds__(256) void bktB_or_t1(
    const uint2* ebuf, const int* gcur, const int* bbase, int cap,
    int nbuck, int nodesPerB, int* row_ptr, float* invd, int* col, int N,
    const void* xraw, const int* flags, const float4* Wp1f, const float* b1f,
    unsigned short* t1, unsigned short* s1, int T1B) {
  __shared__ float vx[32 * DD];                // 16 KB (t1 role)
  __shared__ int cnt[MAXNPB];                  // 8 KB  (bucketB role)
  __shared__ int sA[256];
  int b = blockIdx.x;
  int tid = threadIdx.x;

  if (b < nbuck) {                             // ---- bucketB role ----
    int base_node = b * nodesPerB;
    int nn = min(nodesPerB, N - base_node);
    if (nn <= 0) return;
    int nE = min(gcur[b], cap);
    const uint2* ee = ebuf + (size_t)b * cap;
    for (int i = tid; i < nn; i += 256) cnt[i] = 0;
    __syncthreads();
    for (int i = tid; i < nE; i += 256)
      atomicAdd(&cnt[(int)ee[i].y - base_node], 1);
    __syncthreads();
    // blocked exclusive scan over cnt[0..nn)
    int per = (nn + 255) / 256;                // <= 8
    int myb = tid * per;
    int dreg[8];
    int ssum = 0;
#pragma unroll
    for (int k = 0; k < 8; k++) {
      int idx = myb + k;
      int v = (k < per && idx < nn) ? cnt[idx] : 0;
      dreg[k] = v; ssum += v;
    }
    sA[tid] = ssum;
    __syncthreads();
    for (int st = 1; st < 256; st <<= 1) {
      int t = (tid >= st) ? sA[tid - st] : 0;
      __syncthreads();
      sA[tid] += t;
      __syncthreads();
    }
    int run = bbase[b] + sA[tid] - ssum;
    __syncthreads();
#pragma unroll
    for (int k = 0; k < 8; k++) {
      int idx = myb + k;
      if (k < per && idx < nn) {
        row_ptr[base_node + idx] = run;
        invd[base_node + idx] = 1.0f / (float)max(dreg[k], 1);
        cnt[idx] = run;                        // becomes absolute fill cursor
        run += dreg[k];
      }
    }
    __syncthreads();
    for (int i = tid; i < nE; i += 256) {
      uint2 eg = ee[i];
      int p = atomicAdd(&cnt[(int)eg.y - base_node], 1);
      col[p] = (int)eg.x;                      // write confined to ~100KB window
    }
    return;
  }

  // ---- transform1 role ----
  int t = b - nbuck;
  if (t >= T1B) return;
  int wave = tid >> 6, lane = tid & 63;
  int nodeBase = t * 32 + wave * 8;
  float* myv = &vx[wave * 8 * DD];

  if (flags[1]) {                              // fp32 input
    const float2* x2 = (const float2*)xraw;
    for (int k = 0; k < 8; k++) {
      int n = nodeBase + k;
      if (n < N) *(float2*)&myv[k * DD + 2 * lane] = x2[(size_t)n * 64 + lane];
    }
  } else {                                     // bf16 input
    const unsigned int* x32 = (const unsigned int*)xraw;
    for (int k = 0; k < 8; k++) {
      int n = nodeBase + k;
      if (n < N) {
        unsigned int w = x32[(size_t)n * 64 + lane];
        *(float2*)&myv[k * DD + 2 * lane] = make_float2(lo16(w), hi16(w));
      }
    }
  }
  __syncthreads();

  float acct[8] = {0, 0, 0, 0, 0, 0, 0, 0};
  float accs[8] = {0, 0, 0, 0, 0, 0, 0, 0};
  const float2* v2 = (const float2*)myv;
  int j = lane;
  for (int p = 0; p < 64; p++) {
    float4 w = Wp1f[p * 64 + j];
#pragma unroll
    for (int k = 0; k < 8; k++) {
      float2 vv = v2[k * 64 + p];
      acct[k] += vv.x * w.x + vv.y * w.y;
      accs[k] += vv.x * w.z + vv.y * w.w;
    }
  }
  float bb = b1f[j];
  for (int k = 0; k < 8; k++) {
    int n = nodeBase + k;
    if (n < N) {
      t1[n * HH + j] = f2bf(acct[k]);
      s1[n * HH + j] = f2bf(accs[k] + bb);
    }
  }
}

// ---------- vectorized CSR mean-gather (128B rows) ----------
__device__ __forceinline__ void gather_rows(const uint4* t8, const int* col,
                                            int start, int end, int r, int c,
                                            float acc[8]) {
  for (int base = start; base < end; base += 16) {
    int i0 = base + r, i1 = base + 8 + r;
    uint4 v0 = make_uint4(0, 0, 0, 0), v1 = make_uint4(0, 0, 0, 0);
    bool g0 = (i0 < end), g1 = (i1 < end);
    int nb0 = g0 ? col[i0] : 0;
    int nb1 = g1 ? col[i1] : 0;
    if (g0) v0 = t8[nb0 * 8 + c];
    if (g1) v1 = t8[nb1 * 8 + c];
    acc[0] += lo16(v0.x) + lo16(v1.x);
    acc[1] += hi16(v0.x) + hi16(v1.x);
    acc[2] += lo16(v0.y) + lo16(v1.y);
    acc[3] += hi16(v0.y) + hi16(v1.y);
    acc[4] += lo16(v0.z) + lo16(v1.z);
    acc[5] += hi16(v0.z) + hi16(v1.z);
    acc[6] += lo16(v0.w) + lo16(v1.w);
    acc[7] += hi16(v0.w) + hi16(v1.w);
  }
#pragma unroll
  for (int m = 8; m <= 32; m <<= 1)
#pragma unroll
    for (int i = 0; i < 8; i++) acc[i] += __shfl_xor(acc[i], m, 64);
}

// ---------- aggregate1: h = relu(mean(t1[nbrs]) + s1) ----------
__global__ __launch_bounds__(256) void aggregate1(const unsigned short* t1,
                                                  const unsigned short* s1,
                                                  const int* row_ptr, const float* invd,
                                                  const int* col, unsigned short* h, int N) {
  int wave = threadIdx.x >> 6, lane = threadIdx.x & 63;
  int r = lane >> 3, c = lane & 7;
  int n = blockIdx.x * 4 + wave;
  if (n >= N) return;
  int start = row_ptr[n], end = row_ptr[n + 1];
  float acc[8] = {0, 0, 0, 0, 0, 0, 0, 0};
  gather_rows((const uint4*)t1, col, start, end, r, c, acc);

  if (r == 0) {
    float id = invd[n];
    uint4 sv = ((const uint4*)s1)[n * 8 + c];
    float s[8] = {lo16(sv.x), hi16(sv.x), lo16(sv.y), hi16(sv.y),
                  lo16(sv.z), hi16(sv.z), lo16(sv.w), hi16(sv.w)};
    unsigned int o[4];
#pragma unroll
    for (int i = 0; i < 4; i++) {
      float a0 = fmaxf(acc[2 * i] * id + s[2 * i], 0.f);
      float a1 = fmaxf(acc[2 * i + 1] * id + s[2 * i + 1], 0.f);
      o[i] = (unsigned int)f2bf(a0) | ((unsigned int)f2bf(a1) << 16);
    }
    ((uint4*)h)[n * 8 + c] = make_uint4(o[0], o[1], o[2], o[3]);
  }
}

// ---------- agg2: aggh = mean(h[nbrs]) ----------
__global__ __launch_bounds__(256) void agg2(const unsigned short* h,
                                            const int* row_ptr, const float* invd,
                                            const int* col, unsigned short* aggh, int N) {
  int wave = threadIdx.x >> 6, lane = threadIdx.x & 63;
  int r = lane >> 3, c = lane & 7;
  int n = blockIdx.x * 4 + wave;
  if (n >= N) return;
  int start = row_ptr[n], end = row_ptr[n + 1];
  float acc[8] = {0, 0, 0, 0, 0, 0, 0, 0};
  gather_rows((const uint4*)h, col, start, end, r, c, acc);

  if (r == 0) {
    float id = invd[n];
    unsigned int o[4];
#pragma unroll
    for (int i = 0; i < 4; i++) {
      o[i] = (unsigned int)f2bf(acc[2 * i] * id) |
             ((unsigned int)f2bf(acc[2 * i + 1] * id) << 16);
    }
    ((uint4*)aggh)[n * 8 + c] = make_uint4(o[0], o[1], o[2], o[3]);
  }
}

// ---------- final: out = log_softmax([aggh|h] @ Wcat + b2) ----------
__global__ __launch_bounds__(256) void final_k(const unsigned short* aggh,
                                               const unsigned short* h,
                                               const float2* Wc2f, const float* b2f,
                                               float* out, int N) {
  __shared__ float vx[32 * DD];
  int wave = threadIdx.x >> 6, lane = threadIdx.x & 63;
  int nodeBase = blockIdx.x * 32 + wave * 8;
  float* myv = &vx[wave * 8 * DD];
  int row = lane >> 3, chunk = lane & 7;
  int n0 = nodeBase + row;

  if (n0 < N) {
    uint4 va = ((const uint4*)aggh)[(size_t)n0 * 8 + chunk];
    float* d0 = &myv[row * DD + chunk * 8];
    d0[0] = lo16(va.x); d0[1] = hi16(va.x); d0[2] = lo16(va.y); d0[3] = hi16(va.y);
    d0[4] = lo16(va.z); d0[5] = hi16(va.z); d0[6] = lo16(va.w); d0[7] = hi16(va.w);
    uint4 vh = ((const uint4*)h)[(size_t)n0 * 8 + chunk];
    float* d1 = &myv[row * DD + 64 + chunk * 8];
    d1[0] = lo16(vh.x); d1[1] = hi16(vh.x); d1[2] = lo16(vh.y); d1[3] = hi16(vh.y);
    d1[4] = lo16(vh.z); d1[5] = hi16(vh.z); d1[6] = lo16(vh.w); d1[7] = hi16(vh.w);
  }
  __syncthreads();

  float acc[8] = {0, 0, 0, 0, 0, 0, 0, 0};
  const float2* v2 = (const float2*)myv;
  int j = lane;
  for (int p = 0; p < 64; p++) {
    float2 w = Wc2f[p * 64 + j];
#pragma unroll
    for (int k = 0; k < 8; k++) {
      float2 vv = v2[k * 64 + p];
      acc[k] += vv.x * w.x + vv.y * w.y;
    }
  }
  float bb = (j < CC) ? b2f[j] : 0.f;
  for (int k = 0; k < 8; k++) {
    int n = nodeBase + k;
    float val = (j < CC) ? acc[k] + bb : -INFINITY;
    float m = val;
    for (int off = 32; off > 0; off >>= 1) m = fmaxf(m, __shfl_xor(m, off, 64));
    float e = (j < CC) ? __expf(val - m) : 0.f;
    float ssum = e;
    for (int off = 32; off > 0; off >>= 1) ssum += __shfl_xor(ssum, off, 64);
    if (j < CC && n < N) {
      out[(size_t)n * CC + j] = val - m - __logf(ssum);
    }
  }
}

extern "C" void kernel_launch(void* const* d_in, const int* in_sizes, int n_in,
                              void* d_out, int out_size, void* d_ws, size_t ws_size,
                              hipStream_t stream) {
  const void* x   = d_in[0];
  const int*  e   = (const int*)d_in[1];
  const void* W1l = d_in[2];
  const void* W1r = d_in[3];
  const void* b1  = d_in[4];
  const void* W2l = d_in[5];
  const void* W2r = d_in[6];
  const void* b2  = d_in[7];
  float* out = (float*)d_out;

  const int N = in_sizes[0] / DD;            // 100000
  const int E = in_sizes[1] / 2;             // 1600000
  const int nodesPerB = (N + NBUCK - 1) / NBUCK;   // 1563
  const int nbuck = (N + nodesPerB - 1) / nodesPerB;
  const int cap = (E / NBUCK) * 3 / 2;       // 37500 (+79 sigma for uniform dst)
  const int T1B = (N + 31) / 32;             // 3125

  char* w = (char*)d_ws;
  size_t off = 0;
  auto carve = [&](size_t bytes) -> void* {
    void* p = (void*)(w + off);
    off += (bytes + 255) & ~(size_t)255;
    return p;
  };
  int* col     = (int*)carve((size_t)E * 4);
  int* row_ptr = (int*)carve((size_t)(N + 1) * 4);
  float* invd  = (float*)carve((size_t)N * 4);
  int* gcur    = (int*)carve(NBUCK * 4);
  int* bbase   = (int*)carve((NBUCK + 1) * 4);
  int* flags   = (int*)carve(8);
  unsigned short* t1   = (unsigned short*)carve((size_t)N * HH * 2);
  unsigned short* s1   = (unsigned short*)carve((size_t)N * HH * 2);
  unsigned short* h    = (unsigned short*)carve((size_t)N * HH * 2);
  float4* Wp1f = (float4*)carve(64 * 64 * sizeof(float4));
  float2* Wc2f = (float2*)carve(64 * 64 * sizeof(float2));
  float* b1f   = (float*)carve(HH * sizeof(float));
  float* b2f   = (float*)carve(CC * sizeof(float));
  uint2* ebuf  = (uint2*)carve((size_t)NBUCK * cap * 8);
  unsigned short* aggh = (unsigned short*)ebuf;   // alias: ebuf dead after hybrid
  (void)ws_size; (void)n_in; (void)out_size;

  hipMemsetAsync(gcur, 0, NBUCK * 4, stream);
  detect<<<1, 256, 0, stream>>>((const unsigned int*)e, (const unsigned int*)x, flags);
  bucketA<<<256, 256, 0, stream>>>(e, E, N, flags, nodesPerB, cap, ebuf, gcur);
  bscan_prepw<<<2, 256, 0, stream>>>(gcur, nbuck, cap, bbase, row_ptr, N,
                                     W1l, W1r, b1, W2l, W2r, b2,
                                     flags, Wp1f, Wc2f, b1f, b2f);
  bktB_or_t1<<<nbuck + T1B, 256, 0, stream>>>(ebuf, gcur, bbase, cap,
                                              nbuck, nodesPerB, row_ptr, invd, col, N,
                                              x, flags, Wp1f, b1f, t1, s1, T1B);
  aggregate1<<<(N + 3) / 4, 256, 0, stream>>>(t1, s1, row_ptr, invd, col, h, N);
  agg2<<<(N + 3) / 4, 256, 0, stream>>>(h, row_ptr, invd, col, aggh, N);
  final_k<<<(N + 31) / 32, 256, 0, stream>>>(aggh, h, Wc2f, b2f, out, N);
}

// Round 10
// 350.139 us; speedup vs baseline: 1.2793x; 1.2793x over previous
//
#include <hip/hip_runtime.h>

// ---------- bf16 helpers (raw ushort bit ops, RNE store) ----------
__device__ __forceinline__ float bf2f(unsigned short u) {
  union { unsigned int i; float f; } c; c.i = ((unsigned int)u) << 16; return c.f;
}
__device__ __forceinline__ unsigned short f2bf(float f) {
  union { float f; unsigned int i; } c; c.f = f;
  unsigned int x = c.i;
  return (unsigned short)((x + 0x7fffu + ((x >> 16) & 1u)) >> 16);
}
__device__ __forceinline__ float lo16(unsigned int w) { return bf2f((unsigned short)(w & 0xffffu)); }
__device__ __forceinline__ float hi16(unsigned int w) { return bf2f((unsigned short)(w >> 16)); }

#define DD 128
#define HH 64
#define CC 40
#define NBUCK 64
#define NCHUNK 256        // edge chunks (hist/scatter blocks)
#define MAXNPB 2048       // max nodes per bucket (N <= 131072)

// ---------- dtype detect ----------
__global__ void detect(const unsigned int* e32, const unsigned int* x32, int* flags) {
  __shared__ unsigned int redOr[256];
  __shared__ int redCnt[256];
  int tid = threadIdx.x;
  unsigned int v = 0;
  for (int i = tid; i < 4096; i += 256) v |= e32[2 * i + 1];
  int cnt = 0;
  for (int i = tid; i < 4096; i += 256) {
    unsigned int w = x32[i];
    unsigned int expo = (w >> 7) & 0xffu;
    unsigned short lo = (unsigned short)(w & 0xffffu);
    if (lo == 0 || (expo >= 100u && expo <= 133u)) cnt++;
  }
  redOr[tid] = v; redCnt[tid] = cnt; __syncthreads();
  for (int s = 128; s > 0; s >>= 1) {
    if (tid < s) { redOr[tid] |= redOr[tid + s]; redCnt[tid] += redCnt[tid + s]; }
    __syncthreads();
  }
  if (tid == 0) {
    flags[0] = (redOr[0] == 0u) ? 1 : 0;
    flags[1] = (redCnt[0] < 2048) ? 1 : 0;
  }
}

// ---------- radix pass 1: per-chunk 64-bin histogram ----------
__global__ __launch_bounds__(256) void hist_k(const int* e32, int E, int N,
                                              const int* flags, int nodesPerB,
                                              int* histG) {
  __shared__ int cnt[NBUCK];
  int tid = threadIdx.x;
  if (tid < NBUCK) cnt[tid] = 0;
  __syncthreads();
  int isI64 = flags[0];
  int chunk = (E + NCHUNK - 1) / NCHUNK;
  int e0 = blockIdx.x * chunk, e1 = min(e0 + chunk, E);
  for (int i = e0 + tid; i < e1; i += 256) {
    int d = isI64 ? e32[2 * (E + i)] : e32[E + i];
    d = min(max(d, 0), N - 1);
    atomicAdd(&cnt[d / nodesPerB], 1);
  }
  __syncthreads();
  if (tid < NBUCK) histG[tid * NCHUNK + blockIdx.x] = cnt[tid];
}

// ---------- radix scan (+ prep_w on block 1) ----------
// Exclusive scan of histG[16384] in (bucket,chunk) order -> ohist; bucket starts -> bbase.
__global__ void hscan_prepw(const int* histG, int* ohist, int* bbase, int* row_ptr,
                            int N, int E,
                            const void* W1l, const void* W1r, const void* b1,
                            const void* W2l, const void* W2r, const void* b2,
                            const int* flags, float4* Wp1f, float2* Wc2f,
                            float* b1f, float* b2f) {
  int tid = threadIdx.x;
  if (blockIdx.x == 1) {                       // prep_w role
    int isf = flags[1];
    auto rd = [&](const void* p, int i) -> float {
      return isf ? ((const float*)p)[i] : bf2f(((const unsigned short*)p)[i]);
    };
    auto wcat = [&](int k, int j) -> float {
      return (k < HH) ? rd(W2l, k * CC + j) : rd(W2r, (k - HH) * CC + j);
    };
    for (int idx = tid; idx < 64 * 64; idx += 1024) {
      int p = idx >> 6, j = idx & 63;
      Wp1f[idx] = make_float4(rd(W1l, (2 * p) * HH + j), rd(W1l, (2 * p + 1) * HH + j),
                              rd(W1r, (2 * p) * HH + j), rd(W1r, (2 * p + 1) * HH + j));
      Wc2f[idx] = (j < CC) ? make_float2(wcat(2 * p, j), wcat(2 * p + 1, j))
                           : make_float2(0.f, 0.f);
    }
    if (tid < HH) b1f[tid] = rd(b1, tid);
    if (tid < CC) b2f[tid] = rd(b2, tid);
    return;
  }
  __shared__ int tmp[1024];
  int v[16];
  int base = tid * 16;
  int s = 0;
#pragma unroll
  for (int k = 0; k < 16; k++) { v[k] = histG[base + k]; s += v[k]; }
  tmp[tid] = s; __syncthreads();
  for (int st = 1; st < 1024; st <<= 1) {
    int t = (tid >= st) ? tmp[tid - st] : 0;
    __syncthreads();
    tmp[tid] += t;
    __syncthreads();
  }
  int run = tmp[tid] - s;                      // exclusive prefix
#pragma unroll
  for (int k = 0; k < 16; k++) { ohist[base + k] = run; run += v[k]; }
  __syncthreads();
  if (tid < NBUCK) bbase[tid] = ohist[tid * NCHUNK];
  if (tid == 0) { bbase[NBUCK] = E; row_ptr[N] = E; }
}

// ---------- radix pass 2: scatter edges to bucket-contiguous ebuf ----------
__global__ __launch_bounds__(256) void scatter_k(const int* e32, int E, int N,
                                                 const int* flags, int nodesPerB,
                                                 const int* ohist, uint2* ebuf) {
  __shared__ int cur[NBUCK];
  int tid = threadIdx.x;
  if (tid < NBUCK) cur[tid] = ohist[tid * NCHUNK + blockIdx.x];
  __syncthreads();
  int isI64 = flags[0];
  int chunk = (E + NCHUNK - 1) / NCHUNK;
  int e0 = blockIdx.x * chunk, e1 = min(e0 + chunk, E);
  for (int i = e0 + tid; i < e1; i += 256) {
    int s, d;
    if (isI64) { s = e32[2 * i]; d = e32[2 * (E + i)]; }
    else       { s = e32[i];     d = e32[E + i]; }
    s = min(max(s, 0), N - 1);
    d = min(max(d, 0), N - 1);
    int p = atomicAdd(&cur[d / nodesPerB], 1);
    ebuf[p] = make_uint2((unsigned)s, (unsigned)d);
  }
}

// ---------- hybrid: bucketB (CSR finalize, L2-local) ∥ transform1 (VALU-bound) ----------
// LDS union: vx (16 KB) serves as cnt[2048]+sA[256] in bucketB role.
__global__ __launch_bounds__(256) void bktB_or_t1(
    const uint2* ebuf, const int* bbase,
    int nbuck, int nodesPerB, int* row_ptr, float* invd, int* col, int N,
    const void* xraw, const int* flags, const float4* Wp1f, const float* b1f,
    unsigned short* t1, unsigned short* s1, int T1B) {
  __shared__ float vx[32 * DD];                // 16 KB shared by both roles
  int b = blockIdx.x;
  int tid = threadIdx.x;

  if (b < nbuck) {                             // ---- bucketB role ----
    int* cnt = (int*)vx;                       // [MAXNPB]
    int* sA  = ((int*)vx) + MAXNPB;            // [256]
    int base_node = b * nodesPerB;
    int nn = min(nodesPerB, N - base_node);
    if (nn <= 0) return;
    int eb0 = bbase[b], eb1 = bbase[b + 1];
    int nE = eb1 - eb0;
    const uint2* ee = ebuf + eb0;
    for (int i = tid; i < nn; i += 256) cnt[i] = 0;
    __syncthreads();
    for (int i = tid; i < nE; i += 256)
      atomicAdd(&cnt[(int)ee[i].y - base_node], 1);
    __syncthreads();
    int per = (nn + 255) / 256;                // <= 8
    int myb = tid * per;
    int dreg[8];
    int ssum = 0;
#pragma unroll
    for (int k = 0; k < 8; k++) {
      int idx = myb + k;
      int v = (k < per && idx < nn) ? cnt[idx] : 0;
      dreg[k] = v; ssum += v;
    }
    sA[tid] = ssum;
    __syncthreads();
    for (int st = 1; st < 256; st <<= 1) {
      int t = (tid >= st) ? sA[tid - st] : 0;
      __syncthreads();
      sA[tid] += t;
      __syncthreads();
    }
    int run = eb0 + sA[tid] - ssum;
    __syncthreads();
#pragma unroll
    for (int k = 0; k < 8; k++) {
      int idx = myb + k;
      if (k < per && idx < nn) {
        row_ptr[base_node + idx] = run;
        invd[base_node + idx] = 1.0f / (float)max(dreg[k], 1);
        cnt[idx] = run;                        // absolute fill cursor
        run += dreg[k];
      }
    }
    __syncthreads();
    for (int i = tid; i < nE; i += 256) {
      uint2 eg = ee[i];
      int p = atomicAdd(&cnt[(int)eg.y - base_node], 1);
      col[p] = (int)eg.x;
    }
    return;
  }

  // ---- transform1 role ----
  int t = b - nbuck;
  if (t >= T1B) return;
  int wave = tid >> 6, lane = tid & 63;
  int nodeBase = t * 32 + wave * 8;
  float* myv = &vx[wave * 8 * DD];

  if (flags[1]) {                              // fp32 input
    const float2* x2 = (const float2*)xraw;
    for (int k = 0; k < 8; k++) {
      int n = nodeBase + k;
      if (n < N) *(float2*)&myv[k * DD + 2 * lane] = x2[(size_t)n * 64 + lane];
    }
  } else {                                     // bf16 input
    const unsigned int* x32 = (const unsigned int*)xraw;
    for (int k = 0; k < 8; k++) {
      int n = nodeBase + k;
      if (n < N) {
        unsigned int w = x32[(size_t)n * 64 + lane];
        *(float2*)&myv[k * DD + 2 * lane] = make_float2(lo16(w), hi16(w));
      }
    }
  }
  __syncthreads();

  float acct[8] = {0, 0, 0, 0, 0, 0, 0, 0};
  float accs[8] = {0, 0, 0, 0, 0, 0, 0, 0};
  const float2* v2 = (const float2*)vx + (size_t)wave * 8 * DD / 2;
  int j = lane;
  for (int p = 0; p < 64; p++) {
    float4 w = Wp1f[p * 64 + j];
#pragma unroll
    for (int k = 0; k < 8; k++) {
      float2 vv = v2[k * 64 + p];
      acct[k] += vv.x * w.x + vv.y * w.y;
      accs[k] += vv.x * w.z + vv.y * w.w;
    }
  }
  float bb = b1f[j];
  for (int k = 0; k < 8; k++) {
    int n = nodeBase + k;
    if (n < N) {
      t1[n * HH + j] = f2bf(acct[k]);
      s1[n * HH + j] = f2bf(accs[k] + bb);
    }
  }
}

// ---------- vectorized CSR mean-gather (128B rows) ----------
__device__ __forceinline__ void gather_rows(const uint4* t8, const int* col,
                                            int start, int end, int r, int c,
                                            float acc[8]) {
  for (int base = start; base < end; base += 16) {
    int i0 = base + r, i1 = base + 8 + r;
    uint4 v0 = make_uint4(0, 0, 0, 0), v1 = make_uint4(0, 0, 0, 0);
    bool g0 = (i0 < end), g1 = (i1 < end);
    int nb0 = g0 ? col[i0] : 0;
    int nb1 = g1 ? col[i1] : 0;
    if (g0) v0 = t8[nb0 * 8 + c];
    if (g1) v1 = t8[nb1 * 8 + c];
    acc[0] += lo16(v0.x) + lo16(v1.x);
    acc[1] += hi16(v0.x) + hi16(v1.x);
    acc[2] += lo16(v0.y) + lo16(v1.y);
    acc[3] += hi16(v0.y) + hi16(v1.y);
    acc[4] += lo16(v0.z) + lo16(v1.z);
    acc[5] += hi16(v0.z) + hi16(v1.z);
    acc[6] += lo16(v0.w) + lo16(v1.w);
    acc[7] += hi16(v0.w) + hi16(v1.w);
  }
#pragma unroll
  for (int m = 8; m <= 32; m <<= 1)
#pragma unroll
    for (int i = 0; i < 8; i++) acc[i] += __shfl_xor(acc[i], m, 64);
}

// ---------- aggregate1: h = relu(mean(t1[nbrs]) + s1) ----------
__global__ __launch_bounds__(256) void aggregate1(const unsigned short* t1,
                                                  const unsigned short* s1,
                                                  const int* row_ptr, const float* invd,
                                                  const int* col, unsigned short* h, int N) {
  int wave = threadIdx.x >> 6, lane = threadIdx.x & 63;
  int r = lane >> 3, c = lane & 7;
  int n = blockIdx.x * 4 + wave;
  if (n >= N) return;
  int start = row_ptr[n], end = row_ptr[n + 1];
  float acc[8] = {0, 0, 0, 0, 0, 0, 0, 0};
  gather_rows((const uint4*)t1, col, start, end, r, c, acc);

  if (r == 0) {
    float id = invd[n];
    uint4 sv = ((const uint4*)s1)[n * 8 + c];
    float s[8] = {lo16(sv.x), hi16(sv.x), lo16(sv.y), hi16(sv.y),
                  lo16(sv.z), hi16(sv.z), lo16(sv.w), hi16(sv.w)};
    unsigned int o[4];
#pragma unroll
    for (int i = 0; i < 4; i++) {
      float a0 = fmaxf(acc[2 * i] * id + s[2 * i], 0.f);
      float a1 = fmaxf(acc[2 * i + 1] * id + s[2 * i + 1], 0.f);
      o[i] = (unsigned int)f2bf(a0) | ((unsigned int)f2bf(a1) << 16);
    }
    ((uint4*)h)[n * 8 + c] = make_uint4(o[0], o[1], o[2], o[3]);
  }
}

// ---------- agg2: aggh = mean(h[nbrs]) ----------
__global__ __launch_bounds__(256) void agg2(const unsigned short* h,
                                            const int* row_ptr, const float* invd,
                                            const int* col, unsigned short* aggh, int N) {
  int wave = threadIdx.x >> 6, lane = threadIdx.x & 63;
  int r = lane >> 3, c = lane & 7;
  int n = blockIdx.x * 4 + wave;
  if (n >= N) return;
  int start = row_ptr[n], end = row_ptr[n + 1];
  float acc[8] = {0, 0, 0, 0, 0, 0, 0, 0};
  gather_rows((const uint4*)h, col, start, end, r, c, acc);

  if (r == 0) {
    float id = invd[n];
    unsigned int o[4];
#pragma unroll
    for (int i = 0; i < 4; i++) {
      o[i] = (unsigned int)f2bf(acc[2 * i] * id) |
             ((unsigned int)f2bf(acc[2 * i + 1] * id) << 16);
    }
    ((uint4*)aggh)[n * 8 + c] = make_uint4(o[0], o[1], o[2], o[3]);
  }
}

// ---------- final: out = log_softmax([aggh|h] @ Wcat + b2) ----------
__global__ __launch_bounds__(256) void final_k(const unsigned short* aggh,
                                               const unsigned short* h,
                                               const float2* Wc2f, const float* b2f,
                                               float* out, int N) {
  __shared__ float vx[32 * DD];
  int wave = threadIdx.x >> 6, lane = threadIdx.x & 63;
  int nodeBase = blockIdx.x * 32 + wave * 8;
  float* myv = &vx[wave * 8 * DD];
  int row = lane >> 3, chunk = lane & 7;
  int n0 = nodeBase + row;

  if (n0 < N) {
    uint4 va = ((const uint4*)aggh)[(size_t)n0 * 8 + chunk];
    float* d0 = &myv[row * DD + chunk * 8];
    d0[0] = lo16(va.x); d0[1] = hi16(va.x); d0[2] = lo16(va.y); d0[3] = hi16(va.y);
    d0[4] = lo16(va.z); d0[5] = hi16(va.z); d0[6] = lo16(va.w); d0[7] = hi16(va.w);
    uint4 vh = ((const uint4*)h)[(size_t)n0 * 8 + chunk];
    float* d1 = &myv[row * DD + 64 + chunk * 8];
    d1[0] = lo16(vh.x); d1[1] = hi16(vh.x); d1[2] = lo16(vh.y); d1[3] = hi16(vh.y);
    d1[4] = lo16(vh.z); d1[5] = hi16(vh.z); d1[6] = lo16(vh.w); d1[7] = hi16(vh.w);
  }
  __syncthreads();

  float acc[8] = {0, 0, 0, 0, 0, 0, 0, 0};
  const float2* v2 = (const float2*)myv;
  int j = lane;
  for (int p = 0; p < 64; p++) {
    float2 w = Wc2f[p * 64 + j];
#pragma unroll
    for (int k = 0; k < 8; k++) {
      float2 vv = v2[k * 64 + p];
      acc[k] += vv.x * w.x + vv.y * w.y;
    }
  }
  float bb = (j < CC) ? b2f[j] : 0.f;
  for (int k = 0; k < 8; k++) {
    int n = nodeBase + k;
    float val = (j < CC) ? acc[k] + bb : -INFINITY;
    float m = val;
    for (int off = 32; off > 0; off >>= 1) m = fmaxf(m, __shfl_xor(m, off, 64));
    float e = (j < CC) ? __expf(val - m) : 0.f;
    float ssum = e;
    for (int off = 32; off > 0; off >>= 1) ssum += __shfl_xor(ssum, off, 64);
    if (j < CC && n < N) {
      out[(size_t)n * CC + j] = val - m - __logf(ssum);
    }
  }
}

extern "C" void kernel_launch(void* const* d_in, const int* in_sizes, int n_in,
                              void* d_out, int out_size, void* d_ws, size_t ws_size,
                              hipStream_t stream) {
  const void* x   = d_in[0];
  const int*  e   = (const int*)d_in[1];
  const void* W1l = d_in[2];
  const void* W1r = d_in[3];
  const void* b1  = d_in[4];
  const void* W2l = d_in[5];
  const void* W2r = d_in[6];
  const void* b2  = d_in[7];
  float* out = (float*)d_out;

  const int N = in_sizes[0] / DD;            // 100000
  const int E = in_sizes[1] / 2;             // 1600000
  const int nodesPerB = (N + NBUCK - 1) / NBUCK;   // 1563
  const int nbuck = (N + nodesPerB - 1) / nodesPerB;
  const int T1B = (N + 31) / 32;             // 3125

  char* w = (char*)d_ws;
  size_t off = 0;
  auto carve = [&](size_t bytes) -> void* {
    void* p = (void*)(w + off);
    off += (bytes + 255) & ~(size_t)255;
    return p;
  };
  int* col     = (int*)carve((size_t)E * 4);
  int* row_ptr = (int*)carve((size_t)(N + 1) * 4);
  float* invd  = (float*)carve((size_t)N * 4);
  int* histG   = (int*)carve((size_t)NBUCK * NCHUNK * 4);
  int* ohist   = (int*)carve((size_t)NBUCK * NCHUNK * 4);
  int* bbase   = (int*)carve((NBUCK + 1) * 4);
  int* flags   = (int*)carve(8);
  unsigned short* t1   = (unsigned short*)carve((size_t)N * HH * 2);
  unsigned short* s1   = (unsigned short*)carve((size_t)N * HH * 2);
  unsigned short* h    = (unsigned short*)carve((size_t)N * HH * 2);
  float4* Wp1f = (float4*)carve(64 * 64 * sizeof(float4));
  float2* Wc2f = (float2*)carve(64 * 64 * sizeof(float2));
  float* b1f   = (float*)carve(HH * sizeof(float));
  float* b2f   = (float*)carve(CC * sizeof(float));
  uint2* ebuf  = (uint2*)carve((size_t)E * 8);
  unsigned short* aggh = (unsigned short*)ebuf;   // alias: ebuf dead after hybrid
  (void)ws_size; (void)n_in; (void)out_size;

  detect<<<1, 256, 0, stream>>>((const unsigned int*)e, (const unsigned int*)x, flags);
  hist_k<<<NCHUNK, 256, 0, stream>>>(e, E, N, flags, nodesPerB, histG);
  hscan_prepw<<<2, 1024, 0, stream>>>(histG, ohist, bbase, row_ptr, N, E,
                                      W1l, W1r, b1, W2l, W2r, b2,
                                      flags, Wp1f, Wc2f, b1f, b2f);
  scatter_k<<<NCHUNK, 256, 0, stream>>>(e, E, N, flags, nodesPerB, ohist, ebuf);
  bktB_or_t1<<<nbuck + T1B, 256, 0, stream>>>(ebuf, bbase,
                                              nbuck, nodesPerB, row_ptr, invd, col, N,
                                              x, flags, Wp1f, b1f, t1, s1, T1B);
  aggregate1<<<(N + 3) / 4, 256, 0, stream>>>(t1, s1, row_ptr, invd, col, h, N);
  agg2<<<(N + 3) / 4, 256, 0, stream>>>(h, row_ptr, invd, col, aggh, N);
  final_k<<<(N + 31) / 32, 256, 0, stream>>>(aggh, h, Wc2f, b2f, out, N);
}